// Round 1
// baseline (144.309 us; speedup 1.0000x reference)
//
#include <hip/hip_runtime.h>

#define WS_ 11
#define TX 32
#define TY 32
#define INY 42        // TY + WS_ - 1
#define INX 42        // TX + WS_ - 1
#define ISTR 44       // input tile LDS stride (floats), mult of 4 for float4
#define HSTR 44       // transposed horizontal-sum stride (floats)
#define NTHREADS 256
#define NBUCKETS 256

__global__ __launch_bounds__(NTHREADS) void ssim_main(
    const float* __restrict__ raw, const float* __restrict__ dst,
    const float* __restrict__ win, float* __restrict__ buckets)
{
    __shared__ __align__(16) float sr[INY][ISTR];
    __shared__ __align__(16) float sd[INY][ISTR];
    __shared__ __align__(16) float htr[TX][HSTR];
    __shared__ __align__(16) float htd[TX][HSTR];
    __shared__ __align__(16) float htrr[TX][HSTR];
    __shared__ __align__(16) float htdd[TX][HSTR];
    __shared__ __align__(16) float htrd[TX][HSTR];
    __shared__ float sg[WS_];
    __shared__ float sred[NTHREADS / 64];

    const int tid = threadIdx.x;
    const int gx0 = blockIdx.x * TX;
    const int gy0 = blockIdx.y * TY;
    const long imgoff = (long)blockIdx.z * 512 * 512;
    const float* rbase = raw + imgoff;
    const float* dbase = dst + imgoff;

    // 1D gaussian = row sums of the 2D window (since sum(g)==1)
    if (tid < WS_) {
        float s = 0.f;
        for (int j = 0; j < WS_; ++j) s += win[tid * WS_ + j];
        sg[tid] = s;
    }

    // ---- phase 1: stage input tiles (zero-padded at image edge) ----
    for (int idx = tid; idx < INY * INX; idx += NTHREADS) {
        int row = idx / INX;
        int col = idx - row * INX;
        int gy = gy0 + row, gx = gx0 + col;
        float rv = 0.f, dv = 0.f;
        if (gy < 512 && gx < 512) {
            rv = rbase[gy * 512 + gx];
            dv = dbase[gy * 512 + gx];
        }
        sr[row][col] = rv;
        sd[row][col] = dv;
    }
    __syncthreads();

    float wg[WS_];
#pragma unroll
    for (int k = 0; k < WS_; ++k) wg[k] = sg[k];

    // ---- phase 2: horizontal 11-tap conv of 5 quantities, store transposed ----
    // tasks: 8 x-groups (4 outputs each) x 42 rows = 336
    for (int task = tid; task < 8 * INY; task += NTHREADS) {
        int xg  = task / INY;        // 0..7
        int row = task - xg * INY;   // 0..41
        int x0  = xg * 4;

        float rb[16], db[16];
#pragma unroll
        for (int q = 0; q < 4; ++q) {
            float4 rv = *reinterpret_cast<const float4*>(&sr[row][x0 + 4 * q]);
            float4 dv = *reinterpret_cast<const float4*>(&sd[row][x0 + 4 * q]);
            rb[4 * q + 0] = rv.x; rb[4 * q + 1] = rv.y; rb[4 * q + 2] = rv.z; rb[4 * q + 3] = rv.w;
            db[4 * q + 0] = dv.x; db[4 * q + 1] = dv.y; db[4 * q + 2] = dv.z; db[4 * q + 3] = dv.w;
        }

        float hr[4] = {0.f, 0.f, 0.f, 0.f};
        float hd[4] = {0.f, 0.f, 0.f, 0.f};
        float hrr[4] = {0.f, 0.f, 0.f, 0.f};
        float hdd[4] = {0.f, 0.f, 0.f, 0.f};
        float hrd[4] = {0.f, 0.f, 0.f, 0.f};
#pragma unroll
        for (int k = 0; k < WS_; ++k) {
            float w = wg[k];
#pragma unroll
            for (int xi = 0; xi < 4; ++xi) {
                float r = rb[xi + k], d = db[xi + k];
                float wr = w * r, wd = w * d;
                hr[xi]  += wr;
                hd[xi]  += wd;
                hrr[xi] += wr * r;
                hdd[xi] += wd * d;
                hrd[xi] += wr * d;
            }
        }
#pragma unroll
        for (int xi = 0; xi < 4; ++xi) {
            int x = x0 + xi;
            htr[x][row]  = hr[xi];
            htd[x][row]  = hd[xi];
            htrr[x][row] = hrr[xi];
            htdd[x][row] = hdd[xi];
            htrd[x][row] = hrd[xi];
        }
    }
    __syncthreads();

    // ---- phase 3: vertical 11-tap conv + SSIM + local accumulate ----
    const float C1f = 6.5025f;    // (0.01*255)^2
    const float C2f = 58.5225f;   // (0.03*255)^2
    int x  = tid & (TX - 1);      // 0..31
    int yg = tid >> 5;            // 0..7
    int y0 = yg * 4;

    float b_r[16], b_d[16], b_rr[16], b_dd[16], b_rd[16];
#pragma unroll
    for (int q = 0; q < 4; ++q) {
        float4 v;
        v = *reinterpret_cast<const float4*>(&htr[x][y0 + 4 * q]);
        b_r[4 * q] = v.x; b_r[4 * q + 1] = v.y; b_r[4 * q + 2] = v.z; b_r[4 * q + 3] = v.w;
        v = *reinterpret_cast<const float4*>(&htd[x][y0 + 4 * q]);
        b_d[4 * q] = v.x; b_d[4 * q + 1] = v.y; b_d[4 * q + 2] = v.z; b_d[4 * q + 3] = v.w;
        v = *reinterpret_cast<const float4*>(&htrr[x][y0 + 4 * q]);
        b_rr[4 * q] = v.x; b_rr[4 * q + 1] = v.y; b_rr[4 * q + 2] = v.z; b_rr[4 * q + 3] = v.w;
        v = *reinterpret_cast<const float4*>(&htdd[x][y0 + 4 * q]);
        b_dd[4 * q] = v.x; b_dd[4 * q + 1] = v.y; b_dd[4 * q + 2] = v.z; b_dd[4 * q + 3] = v.w;
        v = *reinterpret_cast<const float4*>(&htrd[x][y0 + 4 * q]);
        b_rd[4 * q] = v.x; b_rd[4 * q + 1] = v.y; b_rd[4 * q + 2] = v.z; b_rd[4 * q + 3] = v.w;
    }

    float lsum = 0.f;
#pragma unroll
    for (int yi = 0; yi < 4; ++yi) {
        float mu1 = 0.f, mu2 = 0.f, s11 = 0.f, s22 = 0.f, s12 = 0.f;
#pragma unroll
        for (int k = 0; k < WS_; ++k) {
            float w = wg[k];
            mu1 += w * b_r[yi + k];
            mu2 += w * b_d[yi + k];
            s11 += w * b_rr[yi + k];
            s22 += w * b_dd[yi + k];
            s12 += w * b_rd[yi + k];
        }
        int ox = gx0 + x, oy = gy0 + y0 + yi;
        if (ox < 502 && oy < 502) {
            float mu1s = mu1 * mu1, mu2s = mu2 * mu2, mu12 = mu1 * mu2;
            float v1 = s11 - mu1s, v2 = s22 - mu2s, cv = s12 - mu12;
            float num = (2.f * mu12 + C1f) * (2.f * cv + C2f);
            float den = (mu1s + mu2s + C1f) * (v1 + v2 + C2f);
            lsum += num / den;
        }
    }

    // ---- block reduction -> bucket atomic ----
#pragma unroll
    for (int off = 32; off; off >>= 1) lsum += __shfl_down(lsum, off);
    if ((tid & 63) == 0) sred[tid >> 6] = lsum;
    __syncthreads();
    if (tid == 0) {
        float s = 0.f;
        for (int w = 0; w < NTHREADS / 64; ++w) s += sred[w];
        int bucket = (blockIdx.x + gridDim.x * blockIdx.y) & (NBUCKETS - 1);
        atomicAdd(&buckets[bucket], s);
    }
}

__global__ void ssim_finalize(const float* __restrict__ buckets,
                              float* __restrict__ out, float inv)
{
    int t = threadIdx.x;
    float s = 0.f;
    for (int i = t; i < NBUCKETS; i += 64) s += buckets[i];
#pragma unroll
    for (int off = 32; off; off >>= 1) s += __shfl_down(s, off);
    if (t == 0) out[0] = s * inv;
}

extern "C" void kernel_launch(void* const* d_in, const int* in_sizes, int n_in,
                              void* d_out, int out_size, void* d_ws, size_t ws_size,
                              hipStream_t stream) {
    const float* raw = (const float*)d_in[0];
    const float* dst = (const float*)d_in[1];
    const float* win = (const float*)d_in[2];
    float* out = (float*)d_out;
    float* buckets = (float*)d_ws;

    int nimg = in_sizes[0] / (512 * 512);        // B*C = 48
    float inv = 1.0f / ((float)nimg * 502.f * 502.f);

    hipMemsetAsync(buckets, 0, NBUCKETS * sizeof(float), stream);

    dim3 grid((502 + TX - 1) / TX, (502 + TY - 1) / TY, nimg);
    ssim_main<<<grid, NTHREADS, 0, stream>>>(raw, dst, win, buckets);
    ssim_finalize<<<1, 64, 0, stream>>>(buckets, out, inv);
}

// Round 2
// 109.693 us; speedup vs baseline: 1.3156x; 1.3156x over previous
//
#include <hip/hip_runtime.h>
#include <hip/hip_fp16.h>

#define WS_ 11
#define TX 32
#define TY 32
#define INY 42
#define INX 42
#define ISTR 44
#define NTHREADS 256
#define NBUCKETS 256

// Transposed horizontal-sum storage (fp16), 5 arrays:
//   element (arr, x, row) -> htall[arr*2048 + x*64 + ((x + (row>>2)) & 15)*4 + (row&3)]
// Per-x 128B row of 16 swizzled 8B chunks; chunk (x,cy) lives at slot (x+cy)&15 so
// column-wise reads (fixed cy across lanes x) hit 16 distinct bank-pairs. [G4/T2]

__device__ __forceinline__ float h2f_elem(const __half2* a, int e) {
    return (e & 1) ? __high2float(a[e >> 1]) : __low2float(a[e >> 1]);
}

__global__ __launch_bounds__(NTHREADS, 4) void ssim_main(
    const float* __restrict__ raw, const float* __restrict__ dst,
    const float* __restrict__ win, float* __restrict__ buckets)
{
    __shared__ __align__(16) float sr[INY][ISTR];
    __shared__ __align__(16) float sd[INY][ISTR];
    __shared__ __align__(16) __half htall[5 * 2048];
    __shared__ float sg[WS_];
    __shared__ float sred[NTHREADS / 64];

    const int tid = threadIdx.x;
    const int gx0 = blockIdx.x * TX;
    const int gy0 = blockIdx.y * TY;
    const long imgoff = (long)blockIdx.z * (512 * 512);
    const float* rbase = raw + imgoff;
    const float* dbase = dst + imgoff;

    // 1D gaussian = row sums of the 2D window (sum(g)==1)
    if (tid < WS_) {
        float s = 0.f;
#pragma unroll
        for (int j = 0; j < WS_; ++j) s += win[tid * WS_ + j];
        sg[tid] = s;
    }

    // ---- phase 1: stage input tiles ----
    const bool interior = (gx0 + ISTR <= 512) && (gy0 + INY <= 512);
    if (interior) {
        // 42 rows x 11 float4 chunks each for r and d; all reads in-image
        for (int c = tid; c < 42 * 11; c += NTHREADS) {
            int row = c / 11;                 // magic-mul
            int c4 = (c - row * 11) * 4;
            long go = (long)(gy0 + row) * 512 + gx0 + c4;
            float4 rv = *reinterpret_cast<const float4*>(rbase + go);
            float4 dv = *reinterpret_cast<const float4*>(dbase + go);
            *reinterpret_cast<float4*>(&sr[row][c4]) = rv;
            *reinterpret_cast<float4*>(&sd[row][c4]) = dv;
        }
    } else {
        for (int idx = tid; idx < INY * ISTR; idx += NTHREADS) {
            int row = idx / ISTR;
            int col = idx - row * ISTR;
            int gy = gy0 + row, gx = gx0 + col;
            float rv = 0.f, dv = 0.f;
            if (gy < 512 && gx < 512) {
                rv = rbase[gy * 512 + gx];
                dv = dbase[gy * 512 + gx];
            }
            sr[row][col] = rv;
            sd[row][col] = dv;
        }
    }
    __syncthreads();

    float wg[WS_];
#pragma unroll
    for (int k = 0; k < WS_; ++k) wg[k] = sg[k];

    // ---- phase 2: horizontal 11-tap conv of 5 quantities -> fp16 transposed ----
    for (int task = tid; task < 8 * INY; task += NTHREADS) {
        int xg = task / INY;                  // magic-mul
        int row = task - xg * INY;
        int x0 = xg * 4;

        float rb[16], db[16];
#pragma unroll
        for (int q = 0; q < 4; ++q) {
            float4 rv = *reinterpret_cast<const float4*>(&sr[row][x0 + 4 * q]);
            float4 dv = *reinterpret_cast<const float4*>(&sd[row][x0 + 4 * q]);
            rb[4*q+0] = rv.x; rb[4*q+1] = rv.y; rb[4*q+2] = rv.z; rb[4*q+3] = rv.w;
            db[4*q+0] = dv.x; db[4*q+1] = dv.y; db[4*q+2] = dv.z; db[4*q+3] = dv.w;
        }

        float hr[4] = {0,0,0,0}, hd[4] = {0,0,0,0};
        float hrr[4] = {0,0,0,0}, hdd[4] = {0,0,0,0}, hrd[4] = {0,0,0,0};
#pragma unroll
        for (int e = 0; e < 14; ++e) {        // scatter form: products computed once
            float r = rb[e], d = db[e];
            float prr = r * r, pdd = d * d, prd = r * d;
#pragma unroll
            for (int xi = 0; xi < 4; ++xi) {
                int k = e - xi;
                if (k >= 0 && k < WS_) {
                    float w = wg[k];
                    hr[xi]  += w * r;   hd[xi]  += w * d;
                    hrr[xi] += w * prr; hdd[xi] += w * pdd; hrd[xi] += w * prd;
                }
            }
        }

        int cy = row >> 2, rl = row & 3;
#pragma unroll
        for (int xi = 0; xi < 4; ++xi) {
            int x = x0 + xi;
            __half* p = &htall[x * 64 + ((x + cy) & 15) * 4 + rl];
            p[0]    = __float2half(hr[xi]);
            p[2048] = __float2half(hd[xi]);
            p[4096] = __float2half(hrr[xi]);
            p[6144] = __float2half(hdd[xi]);
            p[8192] = __float2half(hrd[xi]);
        }
    }
    __syncthreads();

    // ---- phase 3: vertical 11-tap conv + SSIM ----
    const float C1f = 6.5025f, C2f = 58.5225f;
    int x  = tid & 31;
    int yg = tid >> 5;          // 0..7
    int y0 = yg * 4;

    __half2 Ha[8], Hb[8], Hc[8], Hd[8], He[8];
#pragma unroll
    for (int j = 0; j < 4; ++j) {
        const __half* p = &htall[x * 64 + ((x + yg + j) & 15) * 4];
        *reinterpret_cast<uint2*>(&Ha[2*j]) = *reinterpret_cast<const uint2*>(p);
        *reinterpret_cast<uint2*>(&Hb[2*j]) = *reinterpret_cast<const uint2*>(p + 2048);
        *reinterpret_cast<uint2*>(&Hc[2*j]) = *reinterpret_cast<const uint2*>(p + 4096);
        *reinterpret_cast<uint2*>(&Hd[2*j]) = *reinterpret_cast<const uint2*>(p + 6144);
        *reinterpret_cast<uint2*>(&He[2*j]) = *reinterpret_cast<const uint2*>(p + 8192);
    }

    float mu1[4] = {0,0,0,0}, mu2[4] = {0,0,0,0};
    float s11[4] = {0,0,0,0}, s22[4] = {0,0,0,0}, s12[4] = {0,0,0,0};
#pragma unroll
    for (int e = 0; e < 14; ++e) {
        float va = h2f_elem(Ha, e);
        float vb = h2f_elem(Hb, e);
        float vc = h2f_elem(Hc, e);
        float vd = h2f_elem(Hd, e);
        float ve = h2f_elem(He, e);
#pragma unroll
        for (int yi = 0; yi < 4; ++yi) {
            int k = e - yi;
            if (k >= 0 && k < WS_) {
                float w = wg[k];
                mu1[yi] += w * va; mu2[yi] += w * vb;
                s11[yi] += w * vc; s22[yi] += w * vd; s12[yi] += w * ve;
            }
        }
    }

    float lsum = 0.f;
    int ox = gx0 + x;
#pragma unroll
    for (int yi = 0; yi < 4; ++yi) {
        int oy = gy0 + y0 + yi;
        if (ox < 502 && oy < 502) {
            float m1 = mu1[yi], m2 = mu2[yi];
            float m1s = m1 * m1, m2s = m2 * m2, m12 = m1 * m2;
            float v1 = s11[yi] - m1s, v2 = s22[yi] - m2s, cv = s12[yi] - m12;
            float num = (2.f * m12 + C1f) * (2.f * cv + C2f);
            float den = (m1s + m2s + C1f) * (v1 + v2 + C2f);
            lsum += __fdividef(num, den);
        }
    }

    // ---- block reduction -> bucket atomic ----
#pragma unroll
    for (int off = 32; off; off >>= 1) lsum += __shfl_down(lsum, off);
    if ((tid & 63) == 0) sred[tid >> 6] = lsum;
    __syncthreads();
    if (tid == 0) {
        float s = 0.f;
        for (int w = 0; w < NTHREADS / 64; ++w) s += sred[w];
        int bucket = (blockIdx.x + (blockIdx.y << 4) + blockIdx.z * 83) & (NBUCKETS - 1);
        atomicAdd(&buckets[bucket], s);
    }
}

__global__ void ssim_finalize(const float* __restrict__ buckets,
                              float* __restrict__ out, float inv)
{
    int t = threadIdx.x;
    float s = 0.f;
    for (int i = t; i < NBUCKETS; i += 64) s += buckets[i];
#pragma unroll
    for (int off = 32; off; off >>= 1) s += __shfl_down(s, off);
    if (t == 0) out[0] = s * inv;
}

extern "C" void kernel_launch(void* const* d_in, const int* in_sizes, int n_in,
                              void* d_out, int out_size, void* d_ws, size_t ws_size,
                              hipStream_t stream) {
    const float* raw = (const float*)d_in[0];
    const float* dst = (const float*)d_in[1];
    const float* win = (const float*)d_in[2];
    float* out = (float*)d_out;
    float* buckets = (float*)d_ws;

    int nimg = in_sizes[0] / (512 * 512);     // B*C = 48
    float inv = 1.0f / ((float)nimg * 502.f * 502.f);

    hipMemsetAsync(buckets, 0, NBUCKETS * sizeof(float), stream);

    dim3 grid((502 + TX - 1) / TX, (502 + TY - 1) / TY, nimg);
    ssim_main<<<grid, NTHREADS, 0, stream>>>(raw, dst, win, buckets);
    ssim_finalize<<<1, 64, 0, stream>>>(buckets, out, inv);
}

// Round 3
// 79.694 us; speedup vs baseline: 1.8108x; 1.3764x over previous
//
#include <hip/hip_runtime.h>

typedef _Float16 f16x4 __attribute__((ext_vector_type(4)));
typedef float f32x4 __attribute__((ext_vector_type(4)));

#define NBUCKETS 256
#define WT_OFF 1024   // byte offset of weight-frag table in d_ws

// ---------------- pre-kernel: zero buckets + build per-lane weight fragments ----
// Table layout (per lane, 64 halves = 128B):
//   [nt*16 + ks*4 + j]      : Wh B-frag  Wh[c,x]=w[c-x], c=4g+j+16ks, x=ln+16nt
//   [32 + mt*16 + ks*4 + j] : Wv A-frag  Wv[y,r]=w[r-y], r=4g+j+16ks, y=ln+16mt
__global__ void ssim_pre(const float* __restrict__ win, float* __restrict__ ws)
{
    int lane = threadIdx.x;            // 64 threads
#pragma unroll
    for (int i = 0; i < 4; ++i) ws[lane + 64 * i] = 0.f;   // zero buckets

    float w1[11];
#pragma unroll
    for (int i = 0; i < 11; ++i) {
        float s = 0.f;
#pragma unroll
        for (int j = 0; j < 11; ++j) s += win[i * 11 + j];
        w1[i] = s;                     // 1D gaussian (row sums; sum(g)==1)
    }

    _Float16* wt = (_Float16*)((char*)ws + WT_OFF) + lane * 64;
    int g = lane >> 4, ln = lane & 15;
    for (int nt = 0; nt < 2; ++nt)
        for (int ks = 0; ks < 3; ++ks)
            for (int j = 0; j < 4; ++j) {
                int c = 4 * g + j + 16 * ks;
                int idx = c - (ln + 16 * nt);
                wt[nt * 16 + ks * 4 + j] =
                    (_Float16)((idx >= 0 && idx < 11) ? w1[idx] : 0.f);
            }
    for (int mt = 0; mt < 2; ++mt)
        for (int ks = 0; ks < 3; ++ks)
            for (int j = 0; j < 4; ++j) {
                int r = 4 * g + j + 16 * ks;
                int idx = r - (ln + 16 * mt);
                wt[32 + mt * 16 + ks * 4 + j] =
                    (_Float16)((idx >= 0 && idx < 11) ? w1[idx] : 0.f);
            }
}

// ---------------- main kernel: 32x32 output tile per block, 4 waves ----------
__global__ __launch_bounds__(256, 4) void ssim_main(
    const float* __restrict__ raw, const float* __restrict__ dst,
    const float* __restrict__ ws_ro, float* __restrict__ buckets)
{
    // 112B rows (stride 28 banks -> 2-way aliasing = free), no swizzle needed
    __shared__ __align__(16) _Float16 sr[48][56];
    __shared__ __align__(16) _Float16 sd[48][56];
    __shared__ __align__(16) _Float16 ht[5][32][56];   // [q][x][r] transposed H
    __shared__ float sred[4];

    const int tid = threadIdx.x;
    const int wv = tid >> 6;
    const int lane = tid & 63;
    const int g = lane >> 4;
    const int ln = lane & 15;

    const int gx0 = blockIdx.x * 32;
    const int gy0 = blockIdx.y * 32;
    const long ioff = (long)blockIdx.z * (512 * 512);
    const float* rb = raw + ioff;
    const float* db = dst + ioff;

    // per-wave constant weight fragments (L2-hot 8KB table)
    const int nt = wv & 1;        // horiz B ntile AND vert output ntile
    const int mtv = wv >> 1;      // vert output mtile
    const _Float16* wt = (const _Float16*)((const char*)ws_ro + WT_OFF) + lane * 64;
    f16x4 whf[3], wvf[3];
#pragma unroll
    for (int ks = 0; ks < 3; ++ks) {
        whf[ks] = *(const f16x4*)(wt + nt * 16 + ks * 4);
        wvf[ks] = *(const f16x4*)(wt + 32 + mtv * 16 + ks * 4);
    }

    // ---- stage 42x48 f32 -> f16 tiles (rows 42..47 zeroed; cols 48..55 unused)
    const bool interior = (gx0 + 47 < 512) && (gy0 + 41 < 512);
    if (interior) {
        if (tid < 252) {                       // 42 rows x {r,d} x 3 col-sixteenths
            int row = tid / 6;
            int sub = tid - row * 6;
            int arr = sub / 3;
            int third = sub - arr * 3;
            const float* src = (arr ? db : rb) + (long)(gy0 + row) * 512 + gx0 + third * 16;
            float4 f0 = ((const float4*)src)[0];
            float4 f1 = ((const float4*)src)[1];
            float4 f2 = ((const float4*)src)[2];
            float4 f3 = ((const float4*)src)[3];
            union { _Float16 h[16]; uint4 u[2]; } pk;
            pk.h[0] = (_Float16)f0.x; pk.h[1] = (_Float16)f0.y;
            pk.h[2] = (_Float16)f0.z; pk.h[3] = (_Float16)f0.w;
            pk.h[4] = (_Float16)f1.x; pk.h[5] = (_Float16)f1.y;
            pk.h[6] = (_Float16)f1.z; pk.h[7] = (_Float16)f1.w;
            pk.h[8] = (_Float16)f2.x; pk.h[9] = (_Float16)f2.y;
            pk.h[10] = (_Float16)f2.z; pk.h[11] = (_Float16)f2.w;
            pk.h[12] = (_Float16)f3.x; pk.h[13] = (_Float16)f3.y;
            pk.h[14] = (_Float16)f3.z; pk.h[15] = (_Float16)f3.w;
            char* dstp = (char*)(arr ? &sd[0][0] : &sr[0][0]) + row * 112 + third * 32;
            ((uint4*)dstp)[0] = pk.u[0];
            ((uint4*)dstp)[1] = pk.u[1];
        }
        if (tid < 84) {                        // zero rows 42..47 (2 arrays x 7 chunks)
            int arr = tid / 42;
            int rem = tid - arr * 42;
            int row = 42 + rem / 7;
            int ch = rem - (rem / 7) * 7;
            char* dstp = (char*)(arr ? &sd[0][0] : &sr[0][0]) + row * 112 + ch * 16;
            *(uint4*)dstp = make_uint4(0, 0, 0, 0);
        }
    } else {
        for (int idx = tid; idx < 48 * 48; idx += 256) {
            int row = idx / 48;
            int col = idx - row * 48;
            float rv = 0.f, dv = 0.f;
            int gy = gy0 + row, gx = gx0 + col;
            if (row < 42 && gy < 512 && gx < 512) {
                rv = rb[(long)gy * 512 + gx];
                dv = db[(long)gy * 512 + gx];
            }
            sr[row][col] = (_Float16)rv;
            sd[row][col] = (_Float16)dv;
        }
    }
    __syncthreads();

    // ---- horizontal: H[q] = conv_x -> ht[q][x][r], via mfma(R, Wh) ----
    // units (mt,nt): wave w handles u=w and u=w+4 (u<6); nt==wv&1 for both
    for (int u = wv; u < 6; u += 4) {
        int mt = u >> 1;
        f32x4 a0 = {0,0,0,0}, a1 = {0,0,0,0}, a2 = {0,0,0,0},
              a3 = {0,0,0,0}, a4 = {0,0,0,0};
        int row = ln + 16 * mt;
        const char* pr = (const char*)&sr[0][0] + row * 112;
        const char* pd = (const char*)&sd[0][0] + row * 112;
#pragma unroll
        for (int ks = 0; ks < 3; ++ks) {
            int c2 = (4 * g + 16 * ks) * 2;
            f16x4 rA = *(const f16x4*)(pr + c2);
            f16x4 dA = *(const f16x4*)(pd + c2);
            f16x4 rr = rA * rA;
            f16x4 dd = dA * dA;
            f16x4 rd = rA * dA;
            a0 = __builtin_amdgcn_mfma_f32_16x16x16f16(rA, whf[ks], a0, 0, 0, 0);
            a1 = __builtin_amdgcn_mfma_f32_16x16x16f16(dA, whf[ks], a1, 0, 0, 0);
            a2 = __builtin_amdgcn_mfma_f32_16x16x16f16(rr, whf[ks], a2, 0, 0, 0);
            a3 = __builtin_amdgcn_mfma_f32_16x16x16f16(dd, whf[ks], a3, 0, 0, 0);
            a4 = __builtin_amdgcn_mfma_f32_16x16x16f16(rd, whf[ks], a4, 0, 0, 0);
        }
        int x = ln + 16 * nt;              // D col
        int r0 = 4 * g + 16 * mt;          // D first row
        char* hb = (char*)&ht[0][0][0] + x * 112 + r0 * 2;
#define STH(Q, A)                                                        \
        {   union { _Float16 h[4]; uint2 u2; } pk;                       \
            pk.h[0] = (_Float16)A[0]; pk.h[1] = (_Float16)A[1];          \
            pk.h[2] = (_Float16)A[2]; pk.h[3] = (_Float16)A[3];         \
            *(uint2*)(hb + (Q) * 3584) = pk.u2; }
        STH(0, a0) STH(1, a1) STH(2, a2) STH(3, a3) STH(4, a4)
#undef STH
    }
    __syncthreads();

    // ---- vertical: O[q] = mfma(Wv, H) ; each wave owns quadrant (mtv, nt) ----
    f32x4 v0 = {0,0,0,0}, v1 = {0,0,0,0}, v2 = {0,0,0,0},
          v3 = {0,0,0,0}, v4 = {0,0,0,0};
    {
        int x = ln + 16 * nt;              // B col
        const char* hb = (const char*)&ht[0][0][0] + x * 112;
#pragma unroll
        for (int ks = 0; ks < 3; ++ks) {
            int off = (4 * g + 16 * ks) * 2;
            f16x4 B0 = *(const f16x4*)(hb + 0 * 3584 + off);
            f16x4 B1 = *(const f16x4*)(hb + 1 * 3584 + off);
            f16x4 B2 = *(const f16x4*)(hb + 2 * 3584 + off);
            f16x4 B3 = *(const f16x4*)(hb + 3 * 3584 + off);
            f16x4 B4 = *(const f16x4*)(hb + 4 * 3584 + off);
            v0 = __builtin_amdgcn_mfma_f32_16x16x16f16(wvf[ks], B0, v0, 0, 0, 0);
            v1 = __builtin_amdgcn_mfma_f32_16x16x16f16(wvf[ks], B1, v1, 0, 0, 0);
            v2 = __builtin_amdgcn_mfma_f32_16x16x16f16(wvf[ks], B2, v2, 0, 0, 0);
            v3 = __builtin_amdgcn_mfma_f32_16x16x16f16(wvf[ks], B3, v3, 0, 0, 0);
            v4 = __builtin_amdgcn_mfma_f32_16x16x16f16(wvf[ks], B4, v4, 0, 0, 0);
        }
    }

    // ---- SSIM epilogue: lane holds 4 outputs (y=4g+j+16mtv, x=ln+16nt) ----
    float lsum = 0.f;
    {
        int ox = gx0 + ln + 16 * nt;
        int oy0 = gy0 + 4 * g + 16 * mtv;
        if (ox < 502) {
#pragma unroll
            for (int j = 0; j < 4; ++j) {
                if (oy0 + j < 502) {
                    float m1 = v0[j], m2 = v1[j];
                    float m1s = m1 * m1, m2s = m2 * m2, m12 = m1 * m2;
                    float va = v2[j] - m1s, vb = v3[j] - m2s, cv = v4[j] - m12;
                    float num = (2.f * m12 + 6.5025f) * (2.f * cv + 58.5225f);
                    float den = (m1s + m2s + 6.5025f) * (va + vb + 58.5225f);
                    lsum += __fdividef(num, den);
                }
            }
        }
    }
#pragma unroll
    for (int off = 32; off; off >>= 1) lsum += __shfl_down(lsum, off);
    if (lane == 0) sred[wv] = lsum;
    __syncthreads();
    if (tid == 0) {
        float s = sred[0] + sred[1] + sred[2] + sred[3];
        int bucket = (blockIdx.x + (blockIdx.y << 4) + blockIdx.z * 83) & (NBUCKETS - 1);
        atomicAdd(&buckets[bucket], s);
    }
}

__global__ void ssim_finalize(const float* __restrict__ buckets,
                              float* __restrict__ out, float inv)
{
    int t = threadIdx.x;
    float s = 0.f;
    for (int i = t; i < NBUCKETS; i += 64) s += buckets[i];
#pragma unroll
    for (int off = 32; off; off >>= 1) s += __shfl_down(s, off);
    if (t == 0) out[0] = s * inv;
}

extern "C" void kernel_launch(void* const* d_in, const int* in_sizes, int n_in,
                              void* d_out, int out_size, void* d_ws, size_t ws_size,
                              hipStream_t stream) {
    const float* raw = (const float*)d_in[0];
    const float* dst = (const float*)d_in[1];
    const float* win = (const float*)d_in[2];
    float* out = (float*)d_out;
    float* ws = (float*)d_ws;

    int nimg = in_sizes[0] / (512 * 512);     // B*C = 48
    float inv = 1.0f / ((float)nimg * 502.f * 502.f);

    ssim_pre<<<1, 64, 0, stream>>>(win, ws);
    dim3 grid(16, 16, nimg);
    ssim_main<<<grid, 256, 0, stream>>>(raw, dst, ws, ws);
    ssim_finalize<<<1, 64, 0, stream>>>(ws, out, inv);
}